// Round 3
// baseline (834.346 us; speedup 1.0000x reference)
//
#include <hip/hip_runtime.h>
#include <cstdint>
#include <cstddef>

#define E_ 32
#define TOPK_ 4
#define H_ 1024
#define I_ 1024
#define T_ 2048
#define ALPHA_ 1.702f
#define LIMIT_ 7.0f
#define TP_ 66    // transpose LDS pad (elems)

typedef __attribute__((ext_vector_type(8))) short s8;
typedef __attribute__((ext_vector_type(4))) float f4;

__device__ __forceinline__ unsigned short f2bf(float f) {
  unsigned int u = __float_as_uint(f);
  return (unsigned short)((u + 0x7fffu + ((u >> 16) & 1u)) >> 16);
}

// ---------------------------------------------------------------------------
// Kernel 0a: x fp32 -> bf16 streaming cast.
// ---------------------------------------------------------------------------
__global__ __launch_bounds__(256)
void cast_x_kernel(const float* __restrict__ x, unsigned short* __restrict__ xb) {
  size_t i = (size_t)(blockIdx.x * 256 + threadIdx.x) * 8;
  float4 a = *(const float4*)(x + i);
  float4 b = *(const float4*)(x + i + 4);
  s8 v;
  v[0] = (short)f2bf(a.x); v[1] = (short)f2bf(a.y);
  v[2] = (short)f2bf(a.z); v[3] = (short)f2bf(a.w);
  v[4] = (short)f2bf(b.x); v[5] = (short)f2bf(b.y);
  v[6] = (short)f2bf(b.z); v[7] = (short)f2bf(b.w);
  *(s8*)(xb + i) = v;
}

// ---------------------------------------------------------------------------
// Kernel 0b: weight transpose + cast (+ optional gate/up deinterleave).
// ---------------------------------------------------------------------------
__global__ __launch_bounds__(256)
void transpose_cast(const float* __restrict__ src, unsigned short* __restrict__ dst,
                    int src_rows, int src_cols, int deint) {
  int e = blockIdx.z;
  int c0 = blockIdx.x * 64;
  int r0 = blockIdx.y * 64;
  int tid = threadIdx.x;
  __shared__ unsigned short ldsT[64][TP_];   // ldsT[c][r]

  const float* sp = src + (size_t)e * src_rows * src_cols
                        + (size_t)r0 * src_cols + c0;
  int r = tid >> 2, cq = tid & 3;
  const float* rowp = sp + (size_t)r * src_cols + cq * 4;
  #pragma unroll
  for (int j = 0; j < 4; ++j) {
    float4 v = *(const float4*)(rowp + j * 16);
    int c = cq * 4 + j * 16;
    ldsT[c + 0][r] = f2bf(v.x);
    ldsT[c + 1][r] = f2bf(v.y);
    ldsT[c + 2][r] = f2bf(v.z);
    ldsT[c + 3][r] = f2bf(v.w);
  }
  __syncthreads();

  int co = tid >> 2, hq = tid & 3;
  s8 v0 = *(s8*)&ldsT[co][hq * 16];
  s8 v1 = *(s8*)&ldsT[co][hq * 16 + 8];
  int C = c0 + co;
  size_t out_off;
  if (deint) {
    out_off = (size_t)e * src_cols * src_rows
            + (size_t)(C & 1) * (src_cols >> 1) * src_rows
            + (size_t)(C >> 1) * src_rows + r0 + hq * 16;
  } else {
    out_off = (size_t)e * src_cols * src_rows
            + (size_t)C * src_rows + r0 + hq * 16;
  }
  *(s8*)(dst + out_off) = v0;
  *(s8*)(dst + out_off + 8) = v1;
}

// ---------------------------------------------------------------------------
// Kernel 1: router.
// ---------------------------------------------------------------------------
__global__ __launch_bounds__(128)
void router_kernel(const float* __restrict__ x,
                   const float* __restrict__ rw,
                   const float* __restrict__ rb,
                   float* __restrict__ scores,
                   int* __restrict__ counts,
                   int* __restrict__ tok_list,
                   float* __restrict__ w_list) {
  int t = blockIdx.x;
  int tid = threadIdx.x;
  __shared__ float partial[128];
  __shared__ float logits[E_];
  int e = tid & 31, q = tid >> 5;
  const float4* xp = (const float4*)(x + (size_t)t * H_ + q * 256);
  const float4* wp = (const float4*)(rw + (size_t)e * H_ + q * 256);
  float s = 0.f;
  #pragma unroll 8
  for (int h = 0; h < 64; ++h) {
    float4 a = xp[h], b = wp[h];
    s += a.x * b.x + a.y * b.y + a.z * b.z + a.w * b.w;
  }
  partial[tid] = s;
  __syncthreads();
  if (tid < 32)
    logits[tid] = partial[tid] + partial[tid + 32] + partial[tid + 64] +
                  partial[tid + 96] + rb[tid];
  __syncthreads();
  if (tid == 0) {
    float l[E_];
    #pragma unroll
    for (int i = 0; i < E_; ++i) l[i] = logits[i];
    int idx[TOPK_]; float v[TOPK_];
    for (int k = 0; k < TOPK_; ++k) {
      int bi = 0; float bv = -1e30f;
      for (int i = 0; i < E_; ++i)
        if (l[i] > bv) { bv = l[i]; bi = i; }
      idx[k] = bi; v[k] = bv; l[bi] = -1e30f;
    }
    float m = v[0], den = 0.f, w[TOPK_];
    for (int k = 0; k < TOPK_; ++k) { w[k] = expf(v[k] - m); den += w[k]; }
    float inv = 1.f / den;
    float* srow = scores + (size_t)t * E_;
    #pragma unroll
    for (int i = 0; i < E_; ++i) srow[i] = 0.f;
    for (int k = 0; k < TOPK_; ++k) {
      float wk = w[k] * inv;
      srow[idx[k]] = wk;
      int pos = atomicAdd(&counts[idx[k]], 1);
      tok_list[idx[k] * T_ + pos] = t * TOPK_ + k;
      w_list[idx[k] * T_ + pos] = wk;
    }
  }
}

// ---------------------------------------------------------------------------
// MFMA GEMM step macro. A operand comes straight from global (per-wave-private
// gather, double-buffered frags aA/aB). B double-buffered in LDS with XOR
// swizzle (col ^= (row&7)<<3 within the 64-short row) -> bank-uniform b128
// reads AND writes, no padding. 64 MFMA per wave per super-chunk (BK=64).
// ---------------------------------------------------------------------------
#define GEMM_STEP(P, ACUR, ANXT, SCUR, NSC)                                  \
  {                                                                          \
    *(s8*)&Wt[P][n0][wc0] = pB[0];                                           \
    *(s8*)&Wt[P][n0][wc1] = pB[1];                                           \
    *(s8*)&Wt[P][n0][wc2] = pB[2];                                           \
    *(s8*)&Wt[P][n0][wc3] = pB[3];                                           \
    __syncthreads();                                                         \
    if ((SCUR) + 1 < (NSC)) {                                                \
      const unsigned short* bq = bprow + ((SCUR) + 1) * 64 + half * 32;      \
      pB[0] = *(const s8*)(bq);                                              \
      pB[1] = *(const s8*)(bq + 8);                                          \
      pB[2] = *(const s8*)(bq + 16);                                         \
      pB[3] = *(const s8*)(bq + 24);                                         \
      if (wactive) {                                                         \
        _Pragma("unroll")                                                    \
        for (int f = 0; f < 4; ++f) {                                        \
          ANXT[f * 2]     = *(const s8*)(abase[f] + ((SCUR) + 1) * 64);      \
          ANXT[f * 2 + 1] = *(const s8*)(abase[f] + ((SCUR) + 1) * 64 + 32); \
        }                                                                    \
      }                                                                      \
    }                                                                        \
    if (wactive) {                                                           \
      const unsigned short* rb0 = &Wt[P][fm][rcol0];                         \
      const unsigned short* rb1 = &Wt[P][fm][rcol1];                         \
      _Pragma("unroll")                                                      \
      for (int g = 0; g < 8; ++g) {                                          \
        s8 b0 = *(const s8*)(rb0 + g * 1024);                                \
        _Pragma("unroll")                                                    \
        for (int f = 0; f < 4; ++f)                                          \
          acc[f][g] = __builtin_amdgcn_mfma_f32_16x16x32_bf16(               \
              ACUR[f * 2], b0, acc[f][g], 0, 0, 0);                          \
      }                                                                      \
      _Pragma("unroll")                                                      \
      for (int g = 0; g < 8; ++g) {                                          \
        s8 b1 = *(const s8*)(rb1 + g * 1024);                                \
        _Pragma("unroll")                                                    \
        for (int f = 0; f < 4; ++f)                                          \
          acc[f][g] = __builtin_amdgcn_mfma_f32_16x16x32_bf16(               \
              ACUR[f * 2 + 1], b1, acc[f][g], 0, 0, 0);                      \
      }                                                                      \
    }                                                                        \
  }

// ---------------------------------------------------------------------------
// Kernel 2: gate_up. Block = 256 tokens x 128 B-rows (64 gate + 64 up cols),
// 4 waves, wave-tile 64x128 (acc[4][8]).
// ---------------------------------------------------------------------------
__global__ __launch_bounds__(256, 2)
void gateup_mfma(const unsigned short* __restrict__ xb,   // [T][H] bf16
                 const unsigned short* __restrict__ wgu,  // [E][2][I][H] bf16
                 const float* __restrict__ gb,            // [E][2I]
                 const int* __restrict__ counts,
                 const int* __restrict__ tok_list,
                 unsigned short* __restrict__ act) {      // [T*4][I] bf16
  int e = blockIdx.z;
  int cnt = counts[e];
  int t0 = blockIdx.y * 256;
  if (t0 >= cnt) return;
  int itile = blockIdx.x;
  int tid = threadIdx.x;
  int lane = tid & 63;
  int wave = tid >> 6;

  __shared__ __align__(16) unsigned short Wt[2][128][64];
  __shared__ int toks[256];

  {
    int slot = t0 + tid;
    toks[tid] = (slot < cnt) ? tok_list[e * T_ + slot] : -1;
  }
  __syncthreads();

  bool wactive = (t0 + wave * 64) < cnt;
  int fm = lane & 15, ko = (lane >> 4) * 8;

  f4 acc[4][8] = {};

  // A bases: per-wave-private token rows, fragment gather addresses.
  const unsigned short* abase[4];
  #pragma unroll
  for (int f = 0; f < 4; ++f) {
    int enc = toks[wave * 64 + f * 16 + fm];
    int row = (enc < 0) ? 0 : (enc >> 2);
    abase[f] = xb + (size_t)row * H_ + ko;
  }

  // B staging: thread covers row n0, k-half `half` (64 contiguous bytes).
  int n0 = tid & 127, half = tid >> 7;
  const unsigned short* bprow = wgu + (size_t)e * 2 * I_ * H_
      + (size_t)((n0 < 64) ? (itile * 64 + n0) : (I_ + itile * 64 + (n0 - 64))) * H_;
  int wsw = (n0 & 7) << 3;
  int wc0 = (half * 32 + 0)  ^ wsw;
  int wc1 = (half * 32 + 8)  ^ wsw;
  int wc2 = (half * 32 + 16) ^ wsw;
  int wc3 = (half * 32 + 24) ^ wsw;
  int rsw = (fm & 7) << 3;
  int rcol0 = (ko) ^ rsw;
  int rcol1 = (32 + ko) ^ rsw;

  s8 pB[4];
  s8 aA[8], aB[8];
  {
    const unsigned short* bq = bprow + half * 32;
    pB[0] = *(const s8*)(bq);
    pB[1] = *(const s8*)(bq + 8);
    pB[2] = *(const s8*)(bq + 16);
    pB[3] = *(const s8*)(bq + 24);
    if (wactive) {
      #pragma unroll
      for (int f = 0; f < 4; ++f) {
        aA[f * 2]     = *(const s8*)(abase[f]);
        aA[f * 2 + 1] = *(const s8*)(abase[f] + 32);
      }
    }
  }

  for (int s = 0; s < 16; s += 2) {
    GEMM_STEP(0, aA, aB, s, 16)
    GEMM_STEP(1, aB, aA, s + 1, 16)
  }

  int rq = lane >> 4;
  #pragma unroll
  for (int gg = 0; gg < 4; ++gg) {
    int i = itile * 64 + gg * 16 + fm;
    float bg_ = gb[e * 2 * I_ + 2 * i];
    float bu_ = gb[e * 2 * I_ + 2 * i + 1];
    #pragma unroll
    for (int f = 0; f < 4; ++f) {
      #pragma unroll
      for (int r = 0; r < 4; ++r) {
        int m = wave * 64 + f * 16 + rq * 4 + r;
        int enc = toks[m];
        if (enc < 0) continue;
        float gv = acc[f][gg][r] + bg_;
        float uv = acc[f][gg + 4][r] + bu_;
        gv = fminf(gv, LIMIT_);
        uv = fminf(fmaxf(uv, -LIMIT_), LIMIT_);
        float glu = gv / (1.f + __expf(-ALPHA_ * gv));
        act[(size_t)enc * I_ + i] = f2bf((uv + 1.f) * glu);
      }
    }
  }
}

// ---------------------------------------------------------------------------
// Kernel 3: down-proj. Block = 256 tokens x 128 h, same structure.
// ---------------------------------------------------------------------------
__global__ __launch_bounds__(256, 2)
void down_mfma(const unsigned short* __restrict__ act,  // [T*4][I] bf16
               const unsigned short* __restrict__ wdt,  // [E][H][I] bf16
               const float* __restrict__ db,            // [E][H]
               const int* __restrict__ counts,
               const int* __restrict__ tok_list,
               const float* __restrict__ w_list,
               float* __restrict__ dsout) {             // [T*4][H] fp32
  int e = blockIdx.z;
  int cnt = counts[e];
  int t0 = blockIdx.y * 256;
  if (t0 >= cnt) return;
  int htile = blockIdx.x;
  int tid = threadIdx.x;
  int lane = tid & 63;
  int wave = tid >> 6;

  __shared__ __align__(16) unsigned short Wt[2][128][64];
  __shared__ int toks[256];
  __shared__ float tws[256];

  {
    int slot = t0 + tid;
    bool ok = slot < cnt;
    toks[tid] = ok ? tok_list[e * T_ + slot] : -1;
    tws[tid]  = ok ? w_list[e * T_ + slot] : 0.f;
  }
  __syncthreads();

  bool wactive = (t0 + wave * 64) < cnt;
  int fm = lane & 15, ko = (lane >> 4) * 8;

  f4 acc[4][8] = {};

  const unsigned short* abase[4];
  #pragma unroll
  for (int f = 0; f < 4; ++f) {
    int enc = toks[wave * 64 + f * 16 + fm];
    int row = (enc < 0) ? 0 : enc;
    abase[f] = act + (size_t)row * I_ + ko;
  }

  int n0 = tid & 127, half = tid >> 7;
  const unsigned short* bprow = wdt + (size_t)e * H_ * I_
      + (size_t)(htile * 128 + n0) * I_;
  int wsw = (n0 & 7) << 3;
  int wc0 = (half * 32 + 0)  ^ wsw;
  int wc1 = (half * 32 + 8)  ^ wsw;
  int wc2 = (half * 32 + 16) ^ wsw;
  int wc3 = (half * 32 + 24) ^ wsw;
  int rsw = (fm & 7) << 3;
  int rcol0 = (ko) ^ rsw;
  int rcol1 = (32 + ko) ^ rsw;

  s8 pB[4];
  s8 aA[8], aB[8];
  {
    const unsigned short* bq = bprow + half * 32;
    pB[0] = *(const s8*)(bq);
    pB[1] = *(const s8*)(bq + 8);
    pB[2] = *(const s8*)(bq + 16);
    pB[3] = *(const s8*)(bq + 24);
    if (wactive) {
      #pragma unroll
      for (int f = 0; f < 4; ++f) {
        aA[f * 2]     = *(const s8*)(abase[f]);
        aA[f * 2 + 1] = *(const s8*)(abase[f] + 32);
      }
    }
  }

  for (int s = 0; s < 16; s += 2) {
    GEMM_STEP(0, aA, aB, s, 16)
    GEMM_STEP(1, aB, aA, s + 1, 16)
  }

  int rq = lane >> 4;
  #pragma unroll
  for (int g = 0; g < 8; ++g) {
    int h = htile * 128 + g * 16 + fm;
    float bias = db[e * H_ + h];
    #pragma unroll
    for (int f = 0; f < 4; ++f) {
      #pragma unroll
      for (int r = 0; r < 4; ++r) {
        int m = wave * 64 + f * 16 + rq * 4 + r;
        int enc = toks[m];
        if (enc < 0) continue;
        dsout[(size_t)enc * H_ + h] = (acc[f][g][r] + bias) * tws[m];
      }
    }
  }
}

// ---------------------------------------------------------------------------
// Kernel 4: combine — out[t][h] = sum_k dsout[t*4+k][h].
// ---------------------------------------------------------------------------
__global__ __launch_bounds__(256)
void combine_kernel(const float* __restrict__ dsout,
                    float* __restrict__ routed) {
  int idx = blockIdx.x * 256 + threadIdx.x;
  int t = idx >> 8;
  int h = (idx & 255) * 4;
  const float* base = dsout + (size_t)t * 4 * H_ + h;
  float4 a = *(const float4*)(base);
  float4 b = *(const float4*)(base + H_);
  float4 c = *(const float4*)(base + 2 * H_);
  float4 d = *(const float4*)(base + 3 * H_);
  float4 o;
  o.x = a.x + b.x + c.x + d.x;
  o.y = a.y + b.y + c.y + d.y;
  o.z = a.z + b.z + c.z + d.z;
  o.w = a.w + b.w + c.w + d.w;
  *(float4*)(routed + (size_t)t * H_ + h) = o;
}

// ---------------------------------------------------------------------------
extern "C" void kernel_launch(void* const* d_in, const int* in_sizes, int n_in,
                              void* d_out, int out_size, void* d_ws, size_t ws_size,
                              hipStream_t stream) {
  (void)in_sizes; (void)n_in; (void)out_size; (void)ws_size;
  const float* x    = (const float*)d_in[0];
  const float* gup  = (const float*)d_in[1];
  const float* gupb = (const float*)d_in[2];
  const float* dwn  = (const float*)d_in[3];
  const float* dwnb = (const float*)d_in[4];
  const float* rw   = (const float*)d_in[5];
  const float* rb   = (const float*)d_in[6];

  float* routed = (float*)d_out;
  float* scores = (float*)d_out + (size_t)T_ * H_;

  char* ws = (char*)d_ws;
  int*   counts   = (int*)ws;
  int*   tok_list = (int*)(ws + ((size_t)1 << 20));
  float* w_list   = (float*)(ws + ((size_t)1 << 20) + (size_t)E_ * T_ * 4);
  unsigned short* xbf = (unsigned short*)(ws + ((size_t)2 << 20));
  unsigned short* act = (unsigned short*)(ws + ((size_t)8 << 20));
  unsigned short* wgu_b = (unsigned short*)(ws + ((size_t)24 << 20));
  float*          dsout = (float*)(ws + ((size_t)24 << 20));  // alias over wgu
  unsigned short* wdt_b = (unsigned short*)(ws + ((size_t)24 << 20)
                                            + (size_t)E_ * 2 * I_ * H_ * 2);

  hipMemsetAsync(counts, 0, E_ * sizeof(int), stream);

  cast_x_kernel<<<(T_ * H_ / 8) / 256, 256, 0, stream>>>(x, xbf);
  transpose_cast<<<dim3(2 * I_ / 64, H_ / 64, E_), 256, 0, stream>>>(
      gup, wgu_b, H_, 2 * I_, 1);
  transpose_cast<<<dim3(H_ / 64, I_ / 64, E_), 256, 0, stream>>>(
      dwn, wdt_b, I_, H_, 0);
  router_kernel<<<T_, 128, 0, stream>>>(x, rw, rb, scores, counts, tok_list, w_list);
  gateup_mfma<<<dim3(16, 8, 32), 256, 0, stream>>>(xbf, wgu_b, gupb,
                                                   counts, tok_list, act);
  down_mfma<<<dim3(8, 8, 32), 256, 0, stream>>>(act, wdt_b, dwnb,
                                                counts, tok_list, w_list, dsout);
  combine_kernel<<<(T_ * H_ / 4) / 256, 256, 0, stream>>>(dsout, routed);
}

// Round 4
// 738.017 us; speedup vs baseline: 1.1305x; 1.1305x over previous
//
#include <hip/hip_runtime.h>
#include <cstdint>
#include <cstddef>

#define E_ 32
#define TOPK_ 4
#define H_ 1024
#define I_ 1024
#define T_ 2048
#define ALPHA_ 1.702f
#define LIMIT_ 7.0f
#define TP_ 66    // transpose LDS pad (elems)
#define NCH_ 32   // K chunks (K=1024 / BK=32)

typedef __attribute__((ext_vector_type(8))) short s8;
typedef __attribute__((ext_vector_type(4))) float f4;

__device__ __forceinline__ unsigned short f2bf(float f) {
  unsigned int u = __float_as_uint(f);
  return (unsigned short)((u + 0x7fffu + ((u >> 16) & 1u)) >> 16);
}

// async global -> LDS, 16 B per lane. LDS dest must be wave-uniform base;
// HW writes base + lane*16. Global src is per-lane.
__device__ __forceinline__ void gload_lds16(const unsigned short* g,
                                            unsigned short* l) {
  __builtin_amdgcn_global_load_lds(
      (const __attribute__((address_space(1))) void*)g,
      (__attribute__((address_space(3))) void*)l, 16, 0, 0);
}

// ---------------------------------------------------------------------------
// Kernel 0a: x fp32 -> bf16 streaming cast.
// ---------------------------------------------------------------------------
__global__ __launch_bounds__(256)
void cast_x_kernel(const float* __restrict__ x, unsigned short* __restrict__ xb) {
  size_t i = (size_t)(blockIdx.x * 256 + threadIdx.x) * 8;
  float4 a = *(const float4*)(x + i);
  float4 b = *(const float4*)(x + i + 4);
  s8 v;
  v[0] = (short)f2bf(a.x); v[1] = (short)f2bf(a.y);
  v[2] = (short)f2bf(a.z); v[3] = (short)f2bf(a.w);
  v[4] = (short)f2bf(b.x); v[5] = (short)f2bf(b.y);
  v[6] = (short)f2bf(b.z); v[7] = (short)f2bf(b.w);
  *(s8*)(xb + i) = v;
}

// ---------------------------------------------------------------------------
// Kernel 0b: weight transpose + cast (+ optional gate/up deinterleave).
// ---------------------------------------------------------------------------
__global__ __launch_bounds__(256)
void transpose_cast(const float* __restrict__ src, unsigned short* __restrict__ dst,
                    int src_rows, int src_cols, int deint) {
  int e = blockIdx.z;
  int c0 = blockIdx.x * 64;
  int r0 = blockIdx.y * 64;
  int tid = threadIdx.x;
  __shared__ unsigned short ldsT[64][TP_];   // ldsT[c][r]

  const float* sp = src + (size_t)e * src_rows * src_cols
                        + (size_t)r0 * src_cols + c0;
  int r = tid >> 2, cq = tid & 3;
  const float* rowp = sp + (size_t)r * src_cols + cq * 4;
  #pragma unroll
  for (int j = 0; j < 4; ++j) {
    float4 v = *(const float4*)(rowp + j * 16);
    int c = cq * 4 + j * 16;
    ldsT[c + 0][r] = f2bf(v.x);
    ldsT[c + 1][r] = f2bf(v.y);
    ldsT[c + 2][r] = f2bf(v.z);
    ldsT[c + 3][r] = f2bf(v.w);
  }
  __syncthreads();

  int co = tid >> 2, hq = tid & 3;
  s8 v0 = *(s8*)&ldsT[co][hq * 16];
  s8 v1 = *(s8*)&ldsT[co][hq * 16 + 8];
  int C = c0 + co;
  size_t out_off;
  if (deint) {
    out_off = (size_t)e * src_cols * src_rows
            + (size_t)(C & 1) * (src_cols >> 1) * src_rows
            + (size_t)(C >> 1) * src_rows + r0 + hq * 16;
  } else {
    out_off = (size_t)e * src_cols * src_rows
            + (size_t)C * src_rows + r0 + hq * 16;
  }
  *(s8*)(dst + out_off) = v0;
  *(s8*)(dst + out_off + 8) = v1;
}

// ---------------------------------------------------------------------------
// Kernel 1: router.
// ---------------------------------------------------------------------------
__global__ __launch_bounds__(128)
void router_kernel(const float* __restrict__ x,
                   const float* __restrict__ rw,
                   const float* __restrict__ rb,
                   float* __restrict__ scores,
                   int* __restrict__ counts,
                   int* __restrict__ tok_list,
                   float* __restrict__ w_list) {
  int t = blockIdx.x;
  int tid = threadIdx.x;
  __shared__ float partial[128];
  __shared__ float logits[E_];
  int e = tid & 31, q = tid >> 5;
  const float4* xp = (const float4*)(x + (size_t)t * H_ + q * 256);
  const float4* wp = (const float4*)(rw + (size_t)e * H_ + q * 256);
  float s = 0.f;
  #pragma unroll 8
  for (int h = 0; h < 64; ++h) {
    float4 a = xp[h], b = wp[h];
    s += a.x * b.x + a.y * b.y + a.z * b.z + a.w * b.w;
  }
  partial[tid] = s;
  __syncthreads();
  if (tid < 32)
    logits[tid] = partial[tid] + partial[tid + 32] + partial[tid + 64] +
                  partial[tid + 96] + rb[tid];
  __syncthreads();
  if (tid == 0) {
    float l[E_];
    #pragma unroll
    for (int i = 0; i < E_; ++i) l[i] = logits[i];
    int idx[TOPK_]; float v[TOPK_];
    for (int k = 0; k < TOPK_; ++k) {
      int bi = 0; float bv = -1e30f;
      for (int i = 0; i < E_; ++i)
        if (l[i] > bv) { bv = l[i]; bi = i; }
      idx[k] = bi; v[k] = bv; l[bi] = -1e30f;
    }
    float m = v[0], den = 0.f, w[TOPK_];
    for (int k = 0; k < TOPK_; ++k) { w[k] = expf(v[k] - m); den += w[k]; }
    float inv = 1.f / den;
    float* srow = scores + (size_t)t * E_;
    #pragma unroll
    for (int i = 0; i < E_; ++i) srow[i] = 0.f;
    for (int k = 0; k < TOPK_; ++k) {
      float wk = w[k] * inv;
      srow[idx[k]] = wk;
      int pos = atomicAdd(&counts[idx[k]], 1);
      tok_list[idx[k] * T_ + pos] = t * TOPK_ + k;
      w_list[idx[k] * T_ + pos] = wk;
    }
  }
}

// ---------------------------------------------------------------------------
// Kernel 2: gate_up, bf16 MFMA, async pipeline.
// Tile M=64 tokens x N=128 (64 gate + 64 up), 4 waves (wm = wave>>1 m-half,
// wn = wave&1 n-half), 8 MFMA/wave/chunk. Staging: global_load_lds 16B into
// linear double-buffered LDS; raw s_barrier; counted vmcnt(3) (never 0 in
// steady state) so next-next chunk's loads stay in flight across barriers.
// Grid: 1-D, XCD-clustered decode so the 8 token-blocks of one (e, itile)
// run on one XCD -> B slice (256 KB) L2-shared, weights read ~once.
// ---------------------------------------------------------------------------
__global__ __launch_bounds__(256)
void gateup_mfma(const unsigned short* __restrict__ xb,   // [T][H] bf16
                 const unsigned short* __restrict__ wgu,  // [E][2][I][H] bf16
                 const float* __restrict__ gb,            // [E][2I]
                 const int* __restrict__ counts,
                 const int* __restrict__ tok_list,
                 unsigned short* __restrict__ act) {      // [T*4][I] bf16
  // decode: lid = xcd + 8*s ; e = xcd*4 + s>>7 ; w = s&127 ; tblk=w&7 ; itile=w>>3
  int lid = blockIdx.x;
  int xcd = lid & 7, s = lid >> 3;
  int e = (xcd << 2) + (s >> 7);
  int w = s & 127;
  int tblk = w & 7;
  int itile = w >> 3;

  int cnt = counts[e];
  int t0 = tblk * 64;
  if (t0 >= cnt) return;
  int tid = threadIdx.x;
  int lane = tid & 63;
  int wave = tid >> 6;
  int wm = wave >> 1, wn = wave & 1;

  __shared__ __align__(16) unsigned short Xs[2][64][32];
  __shared__ __align__(16) unsigned short Wg[2][128][32];
  __shared__ int toks[64];

  if (tid < 64) {
    int slot = t0 + tid;
    toks[tid] = (slot < cnt) ? tok_list[e * T_ + slot] : -1;
  }
  __syncthreads();

  int fm = lane & 15, ko = (lane >> 4) * 8;
  f4 accg[2][2] = {};
  f4 accu[2][2] = {};

  // per-lane global sources (advance 32 shorts per chunk)
  int arow = (wave << 4) + (lane >> 2);
  int aenc_l = toks[arow];
  const unsigned short* srcA =
      xb + (size_t)((aenc_l < 0) ? 0 : (aenc_l >> 2)) * H_ + ((lane & 3) << 3);
  int br0 = (wave << 5) + (lane >> 2);
  int br1 = br0 + 16;
  size_t R0 = (br0 < 64) ? (size_t)(itile * 64 + br0)
                         : (size_t)(I_ + itile * 64 + (br0 - 64));
  size_t R1 = (br1 < 64) ? (size_t)(itile * 64 + br1)
                         : (size_t)(I_ + itile * 64 + (br1 - 64));
  const unsigned short* wbase = wgu + (size_t)e * 2 * I_ * H_ + ((lane & 3) << 3);
  const unsigned short* srcB0 = wbase + R0 * H_;
  const unsigned short* srcB1 = wbase + R1 * H_;

#define GU_ISSUE(CC, P)                                                      \
  {                                                                          \
    gload_lds16(srcA + (size_t)(CC) * 32, &Xs[P][wave << 4][0]);             \
    gload_lds16(srcB0 + (size_t)(CC) * 32, &Wg[P][wave << 5][0]);            \
    gload_lds16(srcB1 + (size_t)(CC) * 32, &Wg[P][(wave << 5) + 16][0]);     \
  }

  GU_ISSUE(0, 0)
  GU_ISSUE(1, 1)
  asm volatile("s_waitcnt vmcnt(3)" ::: "memory");
  __builtin_amdgcn_s_barrier();
  asm volatile("" ::: "memory");

  for (int c = 0; c < NCH_; ++c) {
    int P = c & 1;
    {
      s8 a0 = *(const s8*)&Xs[P][wm * 32 + fm][ko];
      s8 a1 = *(const s8*)&Xs[P][wm * 32 + 16 + fm][ko];
      #pragma unroll
      for (int g = 0; g < 2; ++g) {
        s8 bg = *(const s8*)&Wg[P][wn * 32 + g * 16 + fm][ko];
        s8 bu = *(const s8*)&Wg[P][64 + wn * 32 + g * 16 + fm][ko];
        accg[0][g] = __builtin_amdgcn_mfma_f32_16x16x32_bf16(a0, bg, accg[0][g], 0, 0, 0);
        accg[1][g] = __builtin_amdgcn_mfma_f32_16x16x32_bf16(a1, bg, accg[1][g], 0, 0, 0);
        accu[0][g] = __builtin_amdgcn_mfma_f32_16x16x32_bf16(a0, bu, accu[0][g], 0, 0, 0);
        accu[1][g] = __builtin_amdgcn_mfma_f32_16x16x32_bf16(a1, bu, accu[1][g], 0, 0, 0);
      }
    }
    __builtin_amdgcn_s_barrier();          // all waves done reading buf P
    asm volatile("" ::: "memory");
    if (c < NCH_ - 2) {
      GU_ISSUE(c + 2, P)
      asm volatile("s_waitcnt vmcnt(3)" ::: "memory");   // chunk c+1 landed
    } else if (c == NCH_ - 2) {
      asm volatile("s_waitcnt vmcnt(0)" ::: "memory");   // drain last chunk
    }
    __builtin_amdgcn_s_barrier();          // publish chunk c+1
    asm volatile("" ::: "memory");
  }
#undef GU_ISSUE

  int rq = lane >> 4;
  #pragma unroll
  for (int g = 0; g < 2; ++g) {
    int i = itile * 64 + wn * 32 + g * 16 + fm;
    float bg_ = gb[e * 2 * I_ + 2 * i];
    float bu_ = gb[e * 2 * I_ + 2 * i + 1];
    #pragma unroll
    for (int f = 0; f < 2; ++f) {
      #pragma unroll
      for (int r = 0; r < 4; ++r) {
        int m = wm * 32 + f * 16 + rq * 4 + r;
        int enc = toks[m];
        if (enc < 0) continue;
        float gv = accg[f][g][r] + bg_;
        float uv = accu[f][g][r] + bu_;
        gv = fminf(gv, LIMIT_);
        uv = fminf(fmaxf(uv, -LIMIT_), LIMIT_);
        float glu = gv / (1.f + __expf(-ALPHA_ * gv));
        act[(size_t)enc * I_ + i] = f2bf((uv + 1.f) * glu);
      }
    }
  }
}

// ---------------------------------------------------------------------------
// Kernel 3: down-proj, same async pipeline. M=64 tokens x N=128 h.
// ---------------------------------------------------------------------------
__global__ __launch_bounds__(256)
void down_mfma(const unsigned short* __restrict__ act,  // [T*4][I] bf16
               const unsigned short* __restrict__ wdt,  // [E][H][I] bf16
               const float* __restrict__ db,            // [E][H]
               const int* __restrict__ counts,
               const int* __restrict__ tok_list,
               const float* __restrict__ w_list,
               float* __restrict__ dsout) {             // [T*4][H] fp32
  // decode: e = (lid&7)*4 + (s>>6) ; w = s&63 ; tblk=w&7 ; htile=w>>3
  int lid = blockIdx.x;
  int xcd = lid & 7, s = lid >> 3;
  int e = (xcd << 2) + (s >> 6);
  int w = s & 63;
  int tblk = w & 7;
  int htile = w >> 3;

  int cnt = counts[e];
  int t0 = tblk * 64;
  if (t0 >= cnt) return;
  int tid = threadIdx.x;
  int lane = tid & 63;
  int wave = tid >> 6;
  int wm = wave >> 1, wn = wave & 1;

  __shared__ __align__(16) unsigned short Xs[2][64][32];
  __shared__ __align__(16) unsigned short Wd[2][128][32];
  __shared__ int toks[64];
  __shared__ float tws[64];

  if (tid < 64) {
    int slot = t0 + tid;
    bool ok = slot < cnt;
    toks[tid] = ok ? tok_list[e * T_ + slot] : -1;
    tws[tid]  = ok ? w_list[e * T_ + slot] : 0.f;
  }
  __syncthreads();

  int fm = lane & 15, ko = (lane >> 4) * 8;
  f4 acc[2][4] = {};

  int arow = (wave << 4) + (lane >> 2);
  int aenc_l = toks[arow];
  const unsigned short* srcA =
      act + (size_t)((aenc_l < 0) ? 0 : aenc_l) * I_ + ((lane & 3) << 3);
  int br0 = (wave << 5) + (lane >> 2);
  int br1 = br0 + 16;
  const unsigned short* wbase = wdt + (size_t)e * H_ * I_ + ((lane & 3) << 3);
  const unsigned short* srcB0 = wbase + (size_t)(htile * 128 + br0) * I_;
  const unsigned short* srcB1 = wbase + (size_t)(htile * 128 + br1) * I_;

#define DN_ISSUE(CC, P)                                                      \
  {                                                                          \
    gload_lds16(srcA + (size_t)(CC) * 32, &Xs[P][wave << 4][0]);             \
    gload_lds16(srcB0 + (size_t)(CC) * 32, &Wd[P][wave << 5][0]);            \
    gload_lds16(srcB1 + (size_t)(CC) * 32, &Wd[P][(wave << 5) + 16][0]);     \
  }

  DN_ISSUE(0, 0)
  DN_ISSUE(1, 1)
  asm volatile("s_waitcnt vmcnt(3)" ::: "memory");
  __builtin_amdgcn_s_barrier();
  asm volatile("" ::: "memory");

  for (int c = 0; c < NCH_; ++c) {
    int P = c & 1;
    {
      s8 a0 = *(const s8*)&Xs[P][wm * 32 + fm][ko];
      s8 a1 = *(const s8*)&Xs[P][wm * 32 + 16 + fm][ko];
      #pragma unroll
      for (int g = 0; g < 4; ++g) {
        s8 b = *(const s8*)&Wd[P][wn * 64 + g * 16 + fm][ko];
        acc[0][g] = __builtin_amdgcn_mfma_f32_16x16x32_bf16(a0, b, acc[0][g], 0, 0, 0);
        acc[1][g] = __builtin_amdgcn_mfma_f32_16x16x32_bf16(a1, b, acc[1][g], 0, 0, 0);
      }
    }
    __builtin_amdgcn_s_barrier();
    asm volatile("" ::: "memory");
    if (c < NCH_ - 2) {
      DN_ISSUE(c + 2, P)
      asm volatile("s_waitcnt vmcnt(3)" ::: "memory");
    } else if (c == NCH_ - 2) {
      asm volatile("s_waitcnt vmcnt(0)" ::: "memory");
    }
    __builtin_amdgcn_s_barrier();
    asm volatile("" ::: "memory");
  }
#undef DN_ISSUE

  int rq = lane >> 4;
  #pragma unroll
  for (int g = 0; g < 4; ++g) {
    int h = htile * 128 + wn * 64 + g * 16 + fm;
    float bias = db[e * H_ + h];
    #pragma unroll
    for (int f = 0; f < 2; ++f) {
      #pragma unroll
      for (int r = 0; r < 4; ++r) {
        int m = wm * 32 + f * 16 + rq * 4 + r;
        int enc = toks[m];
        if (enc < 0) continue;
        dsout[(size_t)enc * H_ + h] = (acc[f][g][r] + bias) * tws[m];
      }
    }
  }
}

// ---------------------------------------------------------------------------
// Kernel 4: combine — out[t][h] = sum_k dsout[t*4+k][h].
// ---------------------------------------------------------------------------
__global__ __launch_bounds__(256)
void combine_kernel(const float* __restrict__ dsout,
                    float* __restrict__ routed) {
  int idx = blockIdx.x * 256 + threadIdx.x;
  int t = idx >> 8;
  int h = (idx & 255) * 4;
  const float* base = dsout + (size_t)t * 4 * H_ + h;
  float4 a = *(const float4*)(base);
  float4 b = *(const float4*)(base + H_);
  float4 c = *(const float4*)(base + 2 * H_);
  float4 d = *(const float4*)(base + 3 * H_);
  float4 o;
  o.x = a.x + b.x + c.x + d.x;
  o.y = a.y + b.y + c.y + d.y;
  o.z = a.z + b.z + c.z + d.z;
  o.w = a.w + b.w + c.w + d.w;
  *(float4*)(routed + (size_t)t * H_ + h) = o;
}

// ---------------------------------------------------------------------------
// Workspace layout: counts@0, tok_list@1MiB, w_list, xbf@2MiB, act@8MiB,
// wgu@24MiB (128MiB, dead after gateup; dsout aliases it), wdt@152MiB (64MiB).
// Total ~216 MiB.
// ---------------------------------------------------------------------------
extern "C" void kernel_launch(void* const* d_in, const int* in_sizes, int n_in,
                              void* d_out, int out_size, void* d_ws, size_t ws_size,
                              hipStream_t stream) {
  (void)in_sizes; (void)n_in; (void)out_size; (void)ws_size;
  const float* x    = (const float*)d_in[0];
  const float* gup  = (const float*)d_in[1];
  const float* gupb = (const float*)d_in[2];
  const float* dwn  = (const float*)d_in[3];
  const float* dwnb = (const float*)d_in[4];
  const float* rw   = (const float*)d_in[5];
  const float* rb   = (const float*)d_in[6];

  float* routed = (float*)d_out;
  float* scores = (float*)d_out + (size_t)T_ * H_;

  char* ws = (char*)d_ws;
  int*   counts   = (int*)ws;
  int*   tok_list = (int*)(ws + ((size_t)1 << 20));
  float* w_list   = (float*)(ws + ((size_t)1 << 20) + (size_t)E_ * T_ * 4);
  unsigned short* xbf = (unsigned short*)(ws + ((size_t)2 << 20));
  unsigned short* act = (unsigned short*)(ws + ((size_t)8 << 20));
  unsigned short* wgu_b = (unsigned short*)(ws + ((size_t)24 << 20));
  float*          dsout = (float*)(ws + ((size_t)24 << 20));  // alias over wgu
  unsigned short* wdt_b = (unsigned short*)(ws + ((size_t)24 << 20)
                                            + (size_t)E_ * 2 * I_ * H_ * 2);

  hipMemsetAsync(counts, 0, E_ * sizeof(int), stream);

  cast_x_kernel<<<(T_ * H_ / 8) / 256, 256, 0, stream>>>(x, xbf);
  transpose_cast<<<dim3(2 * I_ / 64, H_ / 64, E_), 256, 0, stream>>>(
      gup, wgu_b, H_, 2 * I_, 1);
  transpose_cast<<<dim3(H_ / 64, I_ / 64, E_), 256, 0, stream>>>(
      dwn, wdt_b, I_, H_, 0);
  router_kernel<<<T_, 128, 0, stream>>>(x, rw, rb, scores, counts, tok_list, w_list);
  // gateup: 32e x 16 itile x 8 tblk = 4096 blocks, XCD-clustered decode
  gateup_mfma<<<4096, 256, 0, stream>>>(xbf, wgu_b, gupb, counts, tok_list, act);
  // down: 32e x 8 htile x 8 tblk = 2048 blocks
  down_mfma<<<2048, 256, 0, stream>>>(act, wdt_b, dwnb, counts, tok_list,
                                      w_list, dsout);
  combine_kernel<<<(T_ * H_ / 4) / 256, 256, 0, stream>>>(dsout, routed);
}